// Round 9
// baseline (251.290 us; speedup 1.0000x reference)
//
#include <hip/hip_runtime.h>

// Lookahead depthwise conv over time:
//   y[t, b, f] = sum_{k=0..CONTEXT} x[t+k, b, f] * weight[f, k]
// x: (T, B, F) f32, weight: (F, CONTEXT+1) f32, y: (T, B, F) f32.
//
// R5..R9 (resubmits after broker timeouts): R4's float4 regressed because
// LLVM rematerialized the 84-VGPR weight gather inside the loop
// (VGPR_Count=112 = window 96 + nxt 16; weights reloaded per-iter as ~84
// uncoalesced dwords -> VALUBusy 12.7%). Fix:
// (1) amdgpu_waves_per_eu(2,2) so the allocator targets 2 waves/SIMD
//     (~205 VGPR) instead of a 128-VGPR occupancy budget;
// (2) asm-pin the weight registers so the loads cannot be sunk.
// Keep float4 lanes: 1 KB contiguous per wave request (guide: 256 B/wave
// streams cap ~2.8 TB/s, 1 KB/wave reach ~5-6.3 TB/s). TCHUNK=64 -> 512
// blocks = 8 waves/CU; 2 waves/SIMD alternate, each load has ~1344 cy of
// compute cover > ~900 cy HBM latency.

constexpr int T = 2048;
constexpr int B = 16;
constexpr int F = 1024;
constexpr int K = 21;            // CONTEXT + 1
constexpr int BF = B * F;        // 16384 columns
constexpr int CV = BF / 4;       // 4096 float4 columns
constexpr int TCHUNK = 64;       // outputs per thread along t
constexpr int UNROLL = 4;        // outputs per window-shift step
constexpr int BLOCK = 256;

static_assert(TCHUNK % UNROLL == 0, "");
static_assert(T % TCHUNK == 0, "");
static_assert(CV % BLOCK == 0, "");
static_assert(TCHUNK >= K - 1, "preload guard elision requires TCHUNK >= K-1");

__device__ __forceinline__ float4 fma4(float4 a, float4 w, float4 c) {
    return make_float4(fmaf(a.x, w.x, c.x), fmaf(a.y, w.y, c.y),
                       fmaf(a.z, w.z, c.z), fmaf(a.w, w.w, c.w));
}

__global__ __launch_bounds__(BLOCK)
__attribute__((amdgpu_waves_per_eu(2, 2)))
void lookahead_kernel(const float4* __restrict__ x,
                      const float* __restrict__ weight,
                      float4* __restrict__ y)
{
    const int cv = blockIdx.x * BLOCK + threadIdx.x;    // float4 column id
    const int f0 = (cv * 4) & (F - 1);                  // first of 4 features
    const int t0 = blockIdx.y * TCHUNK;

    // Per-thread weights: w[k] = weights of the 4 owned features at tap k.
    // One-time scattered gather (L2-hot after first block); then pinned.
    float4 w[K];
    const float* wp = weight + f0 * K;
    #pragma unroll
    for (int k = 0; k < K; ++k)
        w[k] = make_float4(wp[k], wp[K + k], wp[2 * K + k], wp[3 * K + k]);

    // Pin weights in VGPRs: the empty asm reads+writes each component, so
    // the compiler cannot rematerialize the loads inside the loop (R4 bug).
    #pragma unroll
    for (int k = 0; k < K; ++k)
        asm volatile("" : "+v"(w[k].x), "+v"(w[k].y), "+v"(w[k].z), "+v"(w[k].w));

    const float4* xc = x + cv;
    float4*       yc = y + cv;

    // Sliding window win[j] = x4[t_cur + j] in registers + prefetch buffer.
    float4 win[K - 1 + UNROLL];
    float4 nxt[UNROLL];

    // Preload first K-1 rows. Max index t0 + K - 2 < T since TCHUNK >= K-1.
    #pragma unroll
    for (int k = 0; k < K - 1; ++k)
        win[k] = xc[(t0 + k) * CV];

    // First prefetch batch.
    #pragma unroll
    for (int u = 0; u < UNROLL; ++u) {
        const int tt = t0 + (K - 1) + u;
        nxt[u] = (tt < T) ? xc[tt * CV] : make_float4(0.f, 0.f, 0.f, 0.f);
    }

    for (int tb = 0; tb < TCHUNK; tb += UNROLL) {
        const int t = t0 + tb;

        // Commit prefetched rows into the window.
        #pragma unroll
        for (int u = 0; u < UNROLL; ++u)
            win[K - 1 + u] = nxt[u];

        // Issue next iteration's loads (skip on last iter; uniform branch).
        if (tb + UNROLL < TCHUNK) {
            #pragma unroll
            for (int u = 0; u < UNROLL; ++u) {
                const int tt = t + UNROLL + (K - 1) + u;
                nxt[u] = (tt < T) ? xc[tt * CV]
                                  : make_float4(0.f, 0.f, 0.f, 0.f);
            }
        }

        // Compute UNROLL output rows, 21 packed FMAs each.
        #pragma unroll
        for (int u = 0; u < UNROLL; ++u) {
            float4 acc = make_float4(0.f, 0.f, 0.f, 0.f);
            #pragma unroll
            for (int k = 0; k < K; ++k)
                acc = fma4(win[u + k], w[k], acc);
            yc[(t + u) * CV] = acc;
        }

        // Shift window by UNROLL (static indices -> register moves).
        #pragma unroll
        for (int k = 0; k < K - 1; ++k)
            win[k] = win[k + UNROLL];
    }
}

extern "C" void kernel_launch(void* const* d_in, const int* in_sizes, int n_in,
                              void* d_out, int out_size, void* d_ws, size_t ws_size,
                              hipStream_t stream) {
    const float4* x     = (const float4*)d_in[0];
    const float* weight = (const float*)d_in[1];
    // d_in[2] is tail_padding; always 1 in this benchmark (out_size == T*B*F).
    float4* y = (float4*)d_out;

    dim3 grid(CV / BLOCK, T / TCHUNK);
    lookahead_kernel<<<grid, dim3(BLOCK), 0, stream>>>(x, weight, y);
}

// Round 10
// 244.490 us; speedup vs baseline: 1.0278x; 1.0278x over previous
//
#include <hip/hip_runtime.h>

// Lookahead depthwise conv over time:
//   y[t, b, f] = sum_{k=0..CONTEXT} x[t+k, b, f] * weight[f, k]
// x: (T, B, F) f32, weight: (F, CONTEXT+1) f32, y: (T, B, F) f32.
//
// R10: R4/R9 proved per-thread float4 weights (84 VGPR) always get
// rematerialized (R4, VGPR=112) or scratch-spilled (R9, VGPR=104, asm-pin)
// -> VALUBusy ~12%, 2.2 TB/s. Fix: per-thread weight storage = ZERO.
// Block = 2 b-values x 512 features (1024 cols); the 512 features' weights
// (43 KB) staged once to LDS as [k][fl]; inner loop k-outer/u-inner keeps
// ONE weight float4 live (ds_read_b128 per k, conflict-free). x stays in a
// float4 register sliding window: all global loads/stores 16 B/lane = 1 KB
// contiguous per wave request (the lever past the ~2.8 TB/s 4B-stream cap;
// m18 vs m146). 512 blocks = 2 blocks/CU (LDS cap 3) = 8 waves/CU.

constexpr int T = 2048;
constexpr int B = 16;
constexpr int F = 1024;
constexpr int K = 21;             // CONTEXT + 1
constexpr int BF = B * F;         // 16384 columns
constexpr int CV = BF / 4;        // 4096 float4 columns per t-row
constexpr int FSEG = 512;         // features per block
constexpr int TCHUNK = 64;        // outputs per thread along t
constexpr int UNROLL = 4;         // outputs per window-shift step
constexpr int BLOCK = 256;
constexpr int WFLOATS = FSEG * K; // 10752 floats = 43008 B LDS

static_assert(TCHUNK % UNROLL == 0, "");
static_assert(T % TCHUNK == 0, "");
static_assert(TCHUNK >= K - 1, "preload guard elision requires TCHUNK >= K-1");
static_assert(WFLOATS % BLOCK == 0, "staging loop has no remainder");

__device__ __forceinline__ float4 fma4(float4 a, float4 w, float4 c) {
    return make_float4(fmaf(a.x, w.x, c.x), fmaf(a.y, w.y, c.y),
                       fmaf(a.z, w.z, c.z), fmaf(a.w, w.w, c.w));
}

__global__ __launch_bounds__(BLOCK)
void lookahead_kernel(const float4* __restrict__ x,
                      const float* __restrict__ weight,
                      float4* __restrict__ y)
{
    __shared__ float wlds[WFLOATS];            // [k][fl]: wlds[k*FSEG + fl]

    const int bx    = blockIdx.x;              // 0..15: (b-pair, f-segment)
    const int fseg  = bx & 1;
    const int b0    = (bx >> 1) * 2;
    const int fbase = fseg * FSEG;
    const int tid   = threadIdx.x;

    // Stage this block's 512 features x 21 taps of weights into LDS,
    // transposing [f][k] -> [k][fl]. Coalesced 256 B wave reads; 42/thread.
    {
        const float* wg = weight + fbase * K;  // contiguous 10752 floats
        #pragma unroll
        for (int j = 0; j < WFLOATS / BLOCK; ++j) {
            const int idx = j * BLOCK + tid;
            const float v = wg[idx];
            const int fl  = idx / K;
            const int k   = idx - fl * K;
            wlds[k * FSEG + fl] = v;
        }
    }
    __syncthreads();

    // Thread -> (b, fl): threads 0..127 -> b0, 128..255 -> b0+1;
    // 4 consecutive features per thread -> wave = 1 KB contiguous requests.
    const int b   = b0 + (tid >> 7);
    const int fl  = (tid * 4) & (FSEG - 1);
    const int cv  = (b * F + fbase + fl) >> 2; // float4 column id
    const int flq = fl >> 2;                   // float4 index into a k-row
    const int t0  = blockIdx.y * TCHUNK;

    const float4* xc  = x + cv;
    float4*       yc  = y + cv;
    const float4* wl4 = (const float4*)wlds;   // index: k*(FSEG/4) + flq

    // Sliding window win[j] = x4[t_cur + j] in registers + prefetch buffer.
    float4 win[K - 1 + UNROLL];
    float4 nxt[UNROLL];
    const float4 zero = make_float4(0.f, 0.f, 0.f, 0.f);

    // Preload first K-1 rows (t0 + K - 2 < T since TCHUNK >= K-1).
    #pragma unroll
    for (int k = 0; k < K - 1; ++k)
        win[k] = xc[(t0 + k) * CV];

    // First prefetch batch.
    #pragma unroll
    for (int u = 0; u < UNROLL; ++u) {
        const int tt = t0 + (K - 1) + u;
        nxt[u] = (tt < T) ? xc[tt * CV] : zero;
    }

    for (int tb = 0; tb < TCHUNK; tb += UNROLL) {
        const int t = t0 + tb;

        // Commit prefetched rows into the window.
        #pragma unroll
        for (int u = 0; u < UNROLL; ++u)
            win[K - 1 + u] = nxt[u];

        // Issue next iteration's loads early (uniform guard).
        if (tb + UNROLL < TCHUNK) {
            #pragma unroll
            for (int u = 0; u < UNROLL; ++u) {
                const int tt = t + UNROLL + (K - 1) + u;
                nxt[u] = (tt < T) ? xc[tt * CV] : zero;
            }
        }

        // k-outer / u-inner: exactly ONE weight float4 live at a time
        // (nothing for the register allocator to spill or rematerialize).
        float4 acc[UNROLL];
        #pragma unroll
        for (int u = 0; u < UNROLL; ++u) acc[u] = zero;

        #pragma unroll
        for (int k = 0; k < K; ++k) {
            const float4 wk = wl4[k * (FSEG / 4) + flq];  // ds_read_b128
            #pragma unroll
            for (int u = 0; u < UNROLL; ++u)
                acc[u] = fma4(win[u + k], wk, acc[u]);
        }

        #pragma unroll
        for (int u = 0; u < UNROLL; ++u)
            yc[(t + u) * CV] = acc[u];

        // Shift window by UNROLL (static indices -> register moves).
        #pragma unroll
        for (int k = 0; k < K - 1; ++k)
            win[k] = win[k + UNROLL];
    }
}

extern "C" void kernel_launch(void* const* d_in, const int* in_sizes, int n_in,
                              void* d_out, int out_size, void* d_ws, size_t ws_size,
                              hipStream_t stream) {
    const float4* x     = (const float4*)d_in[0];
    const float* weight = (const float*)d_in[1];
    // d_in[2] is tail_padding; always 1 in this benchmark (out_size == T*B*F).
    float4* y = (float4*)d_out;

    dim3 grid(BF / (BLOCK * 4), T / TCHUNK);   // (16, 32) = 512 blocks
    lookahead_kernel<<<grid, dim3(BLOCK), 0, stream>>>(x, weight, y);
}